// Round 8
// baseline (1360.163 us; speedup 1.0000x reference)
//
#include <hip/hip_runtime.h>
#include <hip/hip_bf16.h>
#include <cstdint>
#include <math.h>

typedef __attribute__((ext_vector_type(4))) float f32x4;
typedef __attribute__((ext_vector_type(8))) __bf16 bf16x8;

__device__ __forceinline__ unsigned short f2bf(float f) {
    union { float f; unsigned u; } v; v.f = f;
    unsigned u = v.u + 0x7fffu + ((v.u >> 16) & 1u);
    return (unsigned short)(u >> 16);
}

__device__ __forceinline__ float gelu_tanh(float x) {
    float x3 = x * x * x;
    float t = tanhf(0.7978845608028654f * (x + 0.044715f * x3));
    return 0.5f * x * (1.0f + t);
}

__device__ __forceinline__ void gload_lds16(const void* g, void* l) {
    __builtin_amdgcn_global_load_lds(
        (__attribute__((address_space(1))) void*)(uintptr_t)g,
        (__attribute__((address_space(3))) void*)(unsigned)(uintptr_t)l,
        16, 0, 0);
}

// ---------------- fused bias-add + residual + LayerNorm ----------------
__global__ __launch_bounds__(256)
void fused_add_ln(const float* __restrict__ in, const float* __restrict__ res,
                  const float* __restrict__ bias, const float* __restrict__ nw,
                  const float* __restrict__ nb, float* __restrict__ resadd,
                  unsigned short* __restrict__ lnout, int H) {
    const int row = blockIdx.x;
    const int tid = threadIdx.x;
    const size_t base = (size_t)row * H;
    float v[16];
    float s = 0.f, ss = 0.f;
#pragma unroll
    for (int i = 0; i < 4; ++i) {
        int idx = (i * 256 + tid) * 4;
        float4 a = *(const float4*)(in + base + idx);
        float4 b = *(const float4*)(res + base + idx);
        float4 c = *(const float4*)(bias + idx);
        float x0 = a.x + b.x + c.x, x1 = a.y + b.y + c.y;
        float x2 = a.z + b.z + c.z, x3 = a.w + b.w + c.w;
        v[i * 4 + 0] = x0; v[i * 4 + 1] = x1; v[i * 4 + 2] = x2; v[i * 4 + 3] = x3;
        s += x0 + x1 + x2 + x3;
        ss += x0 * x0 + x1 * x1 + x2 * x2 + x3 * x3;
    }
#pragma unroll
    for (int off = 32; off > 0; off >>= 1) {
        s += __shfl_down(s, off);
        ss += __shfl_down(ss, off);
    }
    __shared__ float red[8];
    const int w = tid >> 6;
    if ((tid & 63) == 0) { red[w] = s; red[4 + w] = ss; }
    __syncthreads();
    s = red[0] + red[1] + red[2] + red[3];
    ss = red[4] + red[5] + red[6] + red[7];
    const float mean = s / H;
    const float var = ss / H - mean * mean;
    const float rstd = rsqrtf(var + 1e-12f);
#pragma unroll
    for (int i = 0; i < 4; ++i) {
        int idx = (i * 256 + tid) * 4;
        float4 wv = *(const float4*)(nw + idx);
        float4 bv = *(const float4*)(nb + idx);
        float4 r;
        r.x = v[i * 4 + 0]; r.y = v[i * 4 + 1]; r.z = v[i * 4 + 2]; r.w = v[i * 4 + 3];
        *(float4*)(resadd + base + idx) = r;
        ushort4 o;
        o.x = f2bf((r.x - mean) * rstd * wv.x + bv.x);
        o.y = f2bf((r.y - mean) * rstd * wv.y + bv.y);
        o.z = f2bf((r.z - mean) * rstd * wv.z + bv.z);
        o.w = f2bf((r.w - mean) * rstd * wv.w + bv.w);
        *(ushort4*)(lnout + base + idx) = o;
    }
}

// ---------------- fp32 -> bf16 weight cast ----------------
__global__ __launch_bounds__(256)
void cast_w(const float* __restrict__ w, unsigned short* __restrict__ o, long long n4) {
    long long i = (long long)blockIdx.x * 256 + threadIdx.x;
    if (i >= n4) return;
    float4 f = *(const float4*)(w + i * 4);
    ushort4 u;
    u.x = f2bf(f.x); u.y = f2bf(f.y); u.z = f2bf(f.z); u.w = f2bf(f.w);
    *(ushort4*)(o + i * 4) = u;
}

// ------- 256x256 bf16 GEMM, C = A * B^T, 8-phase with READ-AHEAD --------
// 512 thr = 8 waves (2M x 4N), per-wave 128x64. LDS 128 KiB, slot = tile&1.
// R7 finding: same-phase {ds_read -> BAR -> lgkm(0) -> MFMA} exposes the
// LDS drain serially every phase -> MfmaUtil capped ~49%. Fix: phase p
// issues the ds_reads for phase p+1's MFMA (alternate aq bank), then waits
// lgkmcnt(4) = "everything except my 4 new reads" -> the reads feeding THIS
// phase's MFMA were issued a full phase ago (hidden under MFMA + barrier).
// B-frags read same-phase at tile starts (p1/p5): issued BEFORE the A
// pre-reads (order pinned by sched_barrier(0)) so lgkm(4) drains them.
// Tile-crossing pre-reads (p4/p8) placed AFTER {GATE4; BAR}: the barrier
// collectivizes the per-wave vmcnt confirmations before any wave reads the
// freshly staged region (m104 rule).
// Stage order p1..p8: A(s1,T1)h0, A(s1,T1)h1, B(s0,T0+2)h0, B(s0,T0+2)h1,
//                     A(s0,T0+2)h0, A(s0,T0+2)h1, B(s1,T1+2)h0, B(s1,T1+2)h1
// Gates (vmcnt(4) at p4/p8) leave exactly the 2 newest halves in flight;
// every staged region is barrier-separated from its last waited reader.
// Arch-VGPR demand ~94 (aq 2x16 + bq 32 + addr ~30) -> fits the 128 budget
// (acc[8][4] = 128 AGPR; 512-thr block => 256 total/wave hard cap).
#define GBM 256
#define GBN 256
#define GBK 64

#define STAGE(s, mat, h, T) do {                                              \
    const unsigned short* _src = ((mat) ? pB : pA)                            \
        + (size_t)((h) * 128) * K + (size_t)(T) * 64;                         \
    char* _dst = ldsc + (s) * 65536 + (mat) * 32768 + (h) * 16384 + dOff;     \
    gload_lds16(_src, _dst);                                                  \
    gload_lds16(_src + (size_t)64 * K, _dst + 8192);                          \
} while (0)

#define RD_B(s) do {                                                          \
    _Pragma("unroll")                                                         \
    for (int ni = 0; ni < 4; ++ni)                                            \
        _Pragma("unroll")                                                     \
        for (int kk = 0; kk < 2; ++kk)                                        \
            bq[ni][kk] = *(const bf16x8*)(ldsc + (s) * 65536 + 32768          \
                + ((wc * 64 + ni * 16 + lrow) << 7) + ckk[kk]);               \
} while (0)

#define RD_A(bank, q, s) do {                                                 \
    _Pragma("unroll")                                                         \
    for (int m2 = 0; m2 < 2; ++m2)                                            \
        _Pragma("unroll")                                                     \
        for (int kk = 0; kk < 2; ++kk)                                        \
            aq[bank][m2][kk] = *(const bf16x8*)(ldsc + (s) * 65536            \
                + ((wr * 128 + ((q) * 2 + m2) * 16 + lrow) << 7) + ckk[kk]);  \
} while (0)

#define MF(q, bank) do {                                                      \
    __builtin_amdgcn_s_setprio(1);                                            \
    _Pragma("unroll")                                                         \
    for (int m2 = 0; m2 < 2; ++m2)                                            \
        _Pragma("unroll")                                                     \
        for (int ni = 0; ni < 4; ++ni)                                        \
            _Pragma("unroll")                                                 \
            for (int kk = 0; kk < 2; ++kk)                                    \
                acc[(q) * 2 + m2][ni] = __builtin_amdgcn_mfma_f32_16x16x32_bf16( \
                    aq[bank][m2][kk], bq[ni][kk], acc[(q) * 2 + m2][ni], 0, 0, 0); \
    __builtin_amdgcn_s_setprio(0);                                            \
} while (0)

#define BAR asm volatile("s_barrier" ::: "memory")
#define GATE4 asm volatile("s_waitcnt vmcnt(4)" ::: "memory")
#define GATE0 asm volatile("s_waitcnt vmcnt(0)" ::: "memory")
#define LG4 do { asm volatile("s_waitcnt lgkmcnt(4)" ::: "memory");           \
                 __builtin_amdgcn_sched_barrier(0); } while (0)
#define LG0 do { asm volatile("s_waitcnt lgkmcnt(0)" ::: "memory");           \
                 __builtin_amdgcn_sched_barrier(0); } while (0)
#define SB0 __builtin_amdgcn_sched_barrier(0)

template <int EPI>
__global__ __launch_bounds__(512, 2)
void gemm256(const unsigned short* __restrict__ A,
             const unsigned short* __restrict__ B,
             const float* __restrict__ bias_n,
             const float* __restrict__ resadd,
             void* __restrict__ Cout,
             int M, int N, int K) {
    __shared__ unsigned short lds[2][2][2][128 * 64];  // [slot][A/B][half][.]
    char* ldsc = (char*)&lds[0][0][0][0];
    const int tid = threadIdx.x;
    const int lane = tid & 63;
    const int w = tid >> 6;
    const int wr = w >> 2;   // 0..1
    const int wc = w & 3;    // 0..3

    const int nwg = gridDim.x;
    const int lg = (blockIdx.x & 7) * (nwg >> 3) + (blockIdx.x >> 3);
    const int nbx = N / GBN;
    const int brow = lg / nbx;
    const int bcol = lg % nbx;

    // staging source (pre-swizzled so linear LDS write = swizzled layout)
    const int srow = tid >> 3;                                   // 0..63
    const int scol = ((((tid & 7) << 4) ^ ((srow & 7) << 4)) >> 1);
    const unsigned short* pA = A + (size_t)(brow * GBM + srow) * K + scol;
    const unsigned short* pB = B + (size_t)(bcol * GBN + srow) * K + scol;
    const int dOff = tid * 16;

    // ds_read column bytes (swizzled), constant per lane
    const int lrow = lane & 15;
    int ckk[2];
    ckk[0] = (((lane >> 4) << 4)) ^ ((lrow & 7) << 4);
    ckk[1] = ckk[0] ^ 64;

    f32x4 acc[8][4] = {};
    bf16x8 aq[2][2][2];  // [bank][m2][kk] — bank = consuming-phase parity
    bf16x8 bq[4][2];     // per-tile B fragments (reloaded at p1/p5)

    const int NT = K / GBK;
    const int niter = NT / 2;

    // prologue: B(s0,0), A(s0,0), B(s1,1); gate leaves B(s1,1) in flight;
    // post-BAR pre-read of A(s0,q0) into bank0 (region confirmed by gate+BAR)
    STAGE(0, 1, 0, 0); STAGE(0, 1, 1, 0);
    STAGE(0, 0, 0, 0); STAGE(0, 0, 1, 0);
    STAGE(1, 1, 0, 1); STAGE(1, 1, 1, 1);
    GATE4;
    BAR;
    RD_A(0, 0, 0);

    for (int i = 0; i < niter - 1; ++i) {
        const int T0 = 2 * i, T1 = 2 * i + 1;
        // p1: MFMA(q0,s0) <- prologue/p8 pre-read; read B(s0) (drained by LG4)
        RD_B(0); SB0; RD_A(1, 1, 0); STAGE(1, 0, 0, T1);
        BAR; LG4; MF(0, 0); BAR;
        // p2
        RD_A(0, 2, 0); STAGE(1, 0, 1, T1);
        BAR; LG4; MF(1, 1); BAR;
        // p3
        RD_A(1, 3, 0); STAGE(0, 1, 0, T0 + 2);
        BAR; LG4; MF(2, 0); BAR;
        // p4: tile-crossing pre-read AFTER gate+BAR (A(s1,T1) confirmed)
        STAGE(0, 1, 1, T0 + 2); GATE4;
        BAR; RD_A(0, 0, 1); LG4; MF(3, 1); BAR;
        // p5
        RD_B(1); SB0; RD_A(1, 1, 1); STAGE(0, 0, 0, T0 + 2);
        BAR; LG4; MF(0, 0); BAR;
        // p6
        RD_A(0, 2, 1); STAGE(0, 0, 1, T0 + 2);
        BAR; LG4; MF(1, 1); BAR;
        // p7
        RD_A(1, 3, 1); STAGE(1, 1, 0, T1 + 2);
        BAR; LG4; MF(2, 0); BAR;
        // p8: pre-read A(s0,T0+2,q0) AFTER gate+BAR
        STAGE(1, 1, 1, T1 + 2); GATE4;
        BAR; RD_A(0, 0, 0); LG4; MF(3, 1); BAR;
    }
    {   // peeled final iteration (tiles NT-2 in s0, NT-1 in s1)
        const int T1 = NT - 1;
        RD_B(0); SB0; RD_A(1, 1, 0); STAGE(1, 0, 0, T1);
        BAR; LG4; MF(0, 0); BAR;
        RD_A(0, 2, 0); STAGE(1, 0, 1, T1);
        BAR; LG4; MF(1, 1); BAR;
        RD_A(1, 3, 0);
        BAR; LG4; MF(2, 0); BAR;
        GATE0;                       // drain: A(s1,NT-1) + leftover landed
        BAR; RD_A(0, 0, 1); LG4; MF(3, 1); BAR;
        RD_B(1); SB0; RD_A(1, 1, 1);
        BAR; LG4; MF(0, 0); BAR;
        RD_A(0, 2, 1);
        BAR; LG4; MF(1, 1); BAR;
        RD_A(1, 3, 1);
        BAR; LG4; MF(2, 0); BAR;
        LG0; MF(3, 1);
    }

    // epilogue: C/D layout col = lane&15, row = (lane>>4)*4 + j
    const int c0 = bcol * GBN + wc * 64 + lrow;
    const int r0 = brow * GBM + wr * 128 + (lane >> 4) * 4;
#pragma unroll
    for (int mi = 0; mi < 8; ++mi) {
#pragma unroll
        for (int j = 0; j < 4; ++j) {
            const int row = r0 + mi * 16 + j;
#pragma unroll
            for (int ni = 0; ni < 4; ++ni) {
                const int col = c0 + ni * 16;
                float x = acc[mi][ni][j] + bias_n[col];
                if (EPI == 0) {
                    ((unsigned short*)Cout)[(size_t)row * N + col] = f2bf(gelu_tanh(x));
                } else {
                    const size_t off = (size_t)row * N + col;
                    ((float*)Cout)[off] = x + resadd[off];
                }
            }
        }
    }
}

extern "C" void kernel_launch(void* const* d_in, const int* in_sizes, int n_in,
                              void* d_out, int out_size, void* d_ws, size_t ws_size,
                              hipStream_t stream) {
    const float* input    = (const float*)d_in[0];
    const float* residual = (const float*)d_in[1];
    const float* bias     = (const float*)d_in[2];
    const float* attn_nw  = (const float*)d_in[3];
    const float* attn_nb  = (const float*)d_in[4];
    const float* inter_w  = (const float*)d_in[5];
    const float* inter_b  = (const float*)d_in[6];
    const float* output_w = (const float*)d_in[7];
    const float* output_b = (const float*)d_in[8];

    const int H = in_sizes[3];            // 4096
    const int I = in_sizes[6];            // 16384
    const int T = in_sizes[0] / H;        // B*S = 4096

    char* ws = (char*)d_ws;
    float* resadd      = (float*)ws;
    unsigned short* ln = (unsigned short*)(ws + (size_t)T * H * 4);
    unsigned short* w1 = (unsigned short*)((char*)ln + (size_t)T * H * 2);
    unsigned short* w2 = w1 + (size_t)I * H;
    unsigned short* act = w2 + (size_t)H * I;

    fused_add_ln<<<T, 256, 0, stream>>>(input, residual, bias, attn_nw, attn_nb,
                                        resadd, ln, H);

    {
        long long n4 = (long long)I * H / 4;
        int blocks = (int)((n4 + 255) / 256);
        cast_w<<<blocks, 256, 0, stream>>>(inter_w, w1, n4);
        cast_w<<<blocks, 256, 0, stream>>>(output_w, w2, n4);
    }

    // GEMM1: act = gelu(ln @ inter_w^T + inter_b)   [T,I]
    {
        dim3 grid((T / GBM) * (I / GBN));
        gemm256<0><<<grid, 512, 0, stream>>>(ln, w1, inter_b, nullptr, act, T, I, H);
    }

    // GEMM2: out = act @ output_w^T + output_b + resadd   [T,H]
    {
        dim3 grid((T / GBM) * (H / GBN));
        gemm256<1><<<grid, 512, 0, stream>>>(act, w2, output_b, resadd, d_out, T, H, I);
    }
}

// Round 9
// 1278.629 us; speedup vs baseline: 1.0638x; 1.0638x over previous
//
#include <hip/hip_runtime.h>
#include <hip/hip_bf16.h>
#include <cstdint>
#include <math.h>

typedef __attribute__((ext_vector_type(16))) float f32x16;
typedef __attribute__((ext_vector_type(8))) __bf16 bf16x8;

__device__ __forceinline__ unsigned short f2bf(float f) {
    union { float f; unsigned u; } v; v.f = f;
    unsigned u = v.u + 0x7fffu + ((v.u >> 16) & 1u);
    return (unsigned short)(u >> 16);
}

__device__ __forceinline__ float gelu_tanh(float x) {
    float x3 = x * x * x;
    float t = tanhf(0.7978845608028654f * (x + 0.044715f * x3));
    return 0.5f * x * (1.0f + t);
}

__device__ __forceinline__ void gload_lds16(const void* g, void* l) {
    __builtin_amdgcn_global_load_lds(
        (__attribute__((address_space(1))) void*)(uintptr_t)g,
        (__attribute__((address_space(3))) void*)(unsigned)(uintptr_t)l,
        16, 0, 0);
}

// ---------------- fused bias-add + residual + LayerNorm ----------------
__global__ __launch_bounds__(256)
void fused_add_ln(const float* __restrict__ in, const float* __restrict__ res,
                  const float* __restrict__ bias, const float* __restrict__ nw,
                  const float* __restrict__ nb, float* __restrict__ resadd,
                  unsigned short* __restrict__ lnout, int H) {
    const int row = blockIdx.x;
    const int tid = threadIdx.x;
    const size_t base = (size_t)row * H;
    float v[16];
    float s = 0.f, ss = 0.f;
#pragma unroll
    for (int i = 0; i < 4; ++i) {
        int idx = (i * 256 + tid) * 4;
        float4 a = *(const float4*)(in + base + idx);
        float4 b = *(const float4*)(res + base + idx);
        float4 c = *(const float4*)(bias + idx);
        float x0 = a.x + b.x + c.x, x1 = a.y + b.y + c.y;
        float x2 = a.z + b.z + c.z, x3 = a.w + b.w + c.w;
        v[i * 4 + 0] = x0; v[i * 4 + 1] = x1; v[i * 4 + 2] = x2; v[i * 4 + 3] = x3;
        s += x0 + x1 + x2 + x3;
        ss += x0 * x0 + x1 * x1 + x2 * x2 + x3 * x3;
    }
#pragma unroll
    for (int off = 32; off > 0; off >>= 1) {
        s += __shfl_down(s, off);
        ss += __shfl_down(ss, off);
    }
    __shared__ float red[8];
    const int w = tid >> 6;
    if ((tid & 63) == 0) { red[w] = s; red[4 + w] = ss; }
    __syncthreads();
    s = red[0] + red[1] + red[2] + red[3];
    ss = red[4] + red[5] + red[6] + red[7];
    const float mean = s / H;
    const float var = ss / H - mean * mean;
    const float rstd = rsqrtf(var + 1e-12f);
#pragma unroll
    for (int i = 0; i < 4; ++i) {
        int idx = (i * 256 + tid) * 4;
        float4 wv = *(const float4*)(nw + idx);
        float4 bv = *(const float4*)(nb + idx);
        float4 r;
        r.x = v[i * 4 + 0]; r.y = v[i * 4 + 1]; r.z = v[i * 4 + 2]; r.w = v[i * 4 + 3];
        *(float4*)(resadd + base + idx) = r;
        ushort4 o;
        o.x = f2bf((r.x - mean) * rstd * wv.x + bv.x);
        o.y = f2bf((r.y - mean) * rstd * wv.y + bv.y);
        o.z = f2bf((r.z - mean) * rstd * wv.z + bv.z);
        o.w = f2bf((r.w - mean) * rstd * wv.w + bv.w);
        *(ushort4*)(lnout + base + idx) = o;
    }
}

// ---------------- fp32 -> bf16 weight cast ----------------
__global__ __launch_bounds__(256)
void cast_w(const float* __restrict__ w, unsigned short* __restrict__ o, long long n4) {
    long long i = (long long)blockIdx.x * 256 + threadIdx.x;
    if (i >= n4) return;
    float4 f = *(const float4*)(w + i * 4);
    ushort4 u;
    u.x = f2bf(f.x); u.y = f2bf(f.y); u.z = f2bf(f.z); u.w = f2bf(f.w);
    *(ushort4*)(o + i * 4) = u;
}

// ---- 256x256 bf16 GEMM, C = A*B^T: 32x32x16 MFMA, k-slice phases, ------
// ---- read-ahead banks, 2 barriers per 8 phases -------------------------
// 512 thr = 8 waves (2M x 4N), per-wave 128x64 = 4Mx2N tiles of 32x32.
// acc[4][2] f32x16 = 128 AGPR. Frags: aq 2 banks x 4 x 4VGPR = 32,
// bq 2 x 2 x 4 = 16 -> 48 + addr ~25 well under the 128 arch budget.
// Phase t (8 per iter = 2 K-tiles; ks = k-slice K=16):
//   WAIT lgkm(0)+schedbar; 8 MFMA (bank (t-1)&1);
//   [t4,t8: vmcnt(0) gate; BAR]  // stage-loads issued 3 phases ago
//   RD 4A+2B ds_reads (bank t&1) for next phase;
//   [t1: STAGE slot1 tile 2i+1 (8 gloads); t5: STAGE slot0 tile 2i+2]
// Hazards: stage@t1 needs all waves past t8's WAIT -> t8's BAR covers;
// stage@t5 covered by t4's BAR; reads of a freshly staged slot (t4,t8)
// follow {own-gate; BAR} so ALL waves' DMA writes have landed (m104 rule).
// Waves free-run otherwise -> LDS drain overlaps MFMA issue.
#define GBM 256
#define GBN 256

#define STAGE(s, mat, h, T) do {                                              \
    const unsigned short* _src = ((mat) ? pB : pA)                            \
        + (size_t)((h) * 128) * K + (size_t)(T) * 64;                         \
    char* _dst = ldsc + (s) * 65536 + (mat) * 32768 + (h) * 16384 + dOff;     \
    gload_lds16(_src, _dst);                                                  \
    gload_lds16(_src + (size_t)64 * K, _dst + 8192);                          \
} while (0)

#define STG(s, T) do { STAGE(s, 0, 0, T); STAGE(s, 0, 1, T);                  \
                       STAGE(s, 1, 0, T); STAGE(s, 1, 1, T); } while (0)

// ds_reads for k-slice ks of slot s into bank b (4 A + 2 B)
#define RD32(b, ks, s) do {                                                   \
    _Pragma("unroll")                                                         \
    for (int m = 0; m < 4; ++m)                                               \
        aq[b][m] = *(const bf16x8*)(ldsc + (s) * 65536                        \
            + ((wr * 128 + m * 32 + l31) << 7) + ck[ks]);                     \
    _Pragma("unroll")                                                         \
    for (int n = 0; n < 2; ++n)                                               \
        bq[b][n] = *(const bf16x8*)(ldsc + (s) * 65536 + 32768                \
            + ((wc * 64 + n * 32 + l31) << 7) + ck[ks]);                      \
} while (0)

#define MF32(b) do {                                                          \
    __builtin_amdgcn_s_setprio(1);                                            \
    _Pragma("unroll")                                                         \
    for (int m = 0; m < 4; ++m)                                               \
        _Pragma("unroll")                                                     \
        for (int n = 0; n < 2; ++n)                                           \
            acc[m][n] = __builtin_amdgcn_mfma_f32_32x32x16_bf16(              \
                aq[b][m], bq[b][n], acc[m][n], 0, 0, 0);                      \
    __builtin_amdgcn_s_setprio(0);                                            \
} while (0)

#define WAITP do { asm volatile("s_waitcnt lgkmcnt(0)" ::: "memory");         \
                   __builtin_amdgcn_sched_barrier(0); } while (0)
#define BAR   asm volatile("s_barrier" ::: "memory")
#define GATE0 asm volatile("s_waitcnt vmcnt(0)" ::: "memory")

template <int EPI>
__global__ __launch_bounds__(512, 2)
void gemm256(const unsigned short* __restrict__ A,
             const unsigned short* __restrict__ B,
             const float* __restrict__ bias_n,
             const float* __restrict__ resadd,
             void* __restrict__ Cout,
             int M, int N, int K) {
    __shared__ unsigned short lds[2][2][256 * 64];  // [slot][A/B][256r x 64k]
    char* ldsc = (char*)&lds[0][0][0];
    const int tid = threadIdx.x;
    const int lane = tid & 63;
    const int w = tid >> 6;
    const int wr = w >> 2;   // 0..1  (M half)
    const int wc = w & 3;    // 0..3  (N quarter)

    const int nwg = gridDim.x;
    const int lg = (blockIdx.x & 7) * (nwg >> 3) + (blockIdx.x >> 3);
    const int nbx = N / GBN;
    const int brow = lg / nbx;
    const int bcol = lg % nbx;

    // staging source (pre-swizzled so linear LDS write = swizzled layout)
    const int srow = tid >> 3;                                   // 0..63
    const int scol = ((((tid & 7) << 4) ^ ((srow & 7) << 4)) >> 1);
    const unsigned short* pA = A + (size_t)(brow * GBM + srow) * K + scol;
    const unsigned short* pB = B + (size_t)(bcol * GBN + srow) * K + scol;
    const int dOff = tid * 16;

    // ds_read column bytes per k-slice (swizzle ^((row&7)<<4), row&7=lane&7)
    const int l31 = lane & 31;
    int ck[4];
#pragma unroll
    for (int ks = 0; ks < 4; ++ks)
        ck[ks] = ((ks << 5) | (((lane >> 5) & 1) << 4)) ^ ((lane & 7) << 4);

    f32x16 acc[4][2] = {};
    bf16x8 aq[2][4];   // [bank][m-tile]
    bf16x8 bq[2][2];   // [bank][n-tile]

    const int NT = K / 64;
    const int niter = NT / 2;

    // prologue: stage tile0 -> slot0; gate+bar; read ks0 into bank0
    STG(0, 0);
    GATE0; BAR;
    RD32(0, 0, 0);

    for (int i = 0; i < niter - 1; ++i) {
        const int Tn1 = 2 * i + 1, Tn2 = 2 * i + 2;
        WAITP; MF32(0); RD32(1, 1, 0); STG(1, Tn1);     // t1
        WAITP; MF32(1); RD32(0, 2, 0);                  // t2
        WAITP; MF32(0); RD32(1, 3, 0);                  // t3
        WAITP; MF32(1); GATE0; BAR; RD32(0, 0, 1);      // t4 (slot1 ready)
        WAITP; MF32(0); RD32(1, 1, 1); STG(0, Tn2);     // t5
        WAITP; MF32(1); RD32(0, 2, 1);                  // t6
        WAITP; MF32(0); RD32(1, 3, 1);                  // t7
        WAITP; MF32(1); GATE0; BAR; RD32(0, 0, 0);      // t8 (slot0' ready)
    }
    {   // last iteration (tiles NT-2 in slot0, NT-1 in slot1)
        WAITP; MF32(0); RD32(1, 1, 0); STG(1, NT - 1);
        WAITP; MF32(1); RD32(0, 2, 0);
        WAITP; MF32(0); RD32(1, 3, 0);
        WAITP; MF32(1); GATE0; BAR; RD32(0, 0, 1);
        WAITP; MF32(0); RD32(1, 1, 1);
        WAITP; MF32(1); RD32(0, 2, 1);
        WAITP; MF32(0); RD32(1, 3, 1);
        WAITP; MF32(1);
    }

    // epilogue: 32x32 C/D layout col = lane&31,
    // row = (reg&3) + 8*(reg>>2) + 4*(lane>>5)   [m74/m101 verified]
    const int c0 = bcol * GBN + wc * 64 + l31;
    const int r0 = brow * GBM + wr * 128 + ((lane >> 5) & 1) * 4;
#pragma unroll
    for (int m = 0; m < 4; ++m) {
#pragma unroll
        for (int reg = 0; reg < 16; ++reg) {
            const int row = r0 + m * 32 + (reg & 3) + 8 * (reg >> 2);
#pragma unroll
            for (int n = 0; n < 2; ++n) {
                const int col = c0 + n * 32;
                float x = acc[m][n][reg] + bias_n[col];
                if (EPI == 0) {
                    ((unsigned short*)Cout)[(size_t)row * N + col] = f2bf(gelu_tanh(x));
                } else {
                    const size_t off = (size_t)row * N + col;
                    ((float*)Cout)[off] = x + resadd[off];
                }
            }
        }
    }
}

extern "C" void kernel_launch(void* const* d_in, const int* in_sizes, int n_in,
                              void* d_out, int out_size, void* d_ws, size_t ws_size,
                              hipStream_t stream) {
    const float* input    = (const float*)d_in[0];
    const float* residual = (const float*)d_in[1];
    const float* bias     = (const float*)d_in[2];
    const float* attn_nw  = (const float*)d_in[3];
    const float* attn_nb  = (const float*)d_in[4];
    const float* inter_w  = (const float*)d_in[5];
    const float* inter_b  = (const float*)d_in[6];
    const float* output_w = (const float*)d_in[7];
    const float* output_b = (const float*)d_in[8];

    const int H = in_sizes[3];            // 4096
    const int I = in_sizes[6];            // 16384
    const int T = in_sizes[0] / H;        // B*S = 4096

    char* ws = (char*)d_ws;
    float* resadd      = (float*)ws;
    unsigned short* ln = (unsigned short*)(ws + (size_t)T * H * 4);
    unsigned short* w1 = (unsigned short*)((char*)ln + (size_t)T * H * 2);
    unsigned short* w2 = w1 + (size_t)I * H;
    unsigned short* act = w2 + (size_t)H * I;

    fused_add_ln<<<T, 256, 0, stream>>>(input, residual, bias, attn_nw, attn_nb,
                                        resadd, ln, H);

    {
        long long n4 = (long long)I * H / 4;
        int blocks = (int)((n4 + 255) / 256);
        cast_w<<<blocks, 256, 0, stream>>>(inter_w, w1, n4);
        cast_w<<<blocks, 256, 0, stream>>>(output_w, w2, n4);
    }

    // GEMM1: act = gelu(ln @ inter_w^T + inter_b)   [T,I]
    {
        dim3 grid((T / GBM) * (I / GBN));
        gemm256<0><<<grid, 512, 0, stream>>>(ln, w1, inter_b, nullptr, act, T, I, H);
    }

    // GEMM2: out = act @ output_w^T + output_b + resadd   [T,H]
    {
        dim3 grid((T / GBM) * (H / GBN));
        gemm256<1><<<grid, 512, 0, stream>>>(act, w2, output_b, resadd, d_out, T, H, I);
    }
}

// Round 10
// 1278.463 us; speedup vs baseline: 1.0639x; 1.0001x over previous
//
#include <hip/hip_runtime.h>
#include <hip/hip_bf16.h>
#include <cstdint>
#include <math.h>

typedef __attribute__((ext_vector_type(16))) float f32x16;
typedef __attribute__((ext_vector_type(8))) __bf16 bf16x8;

__device__ __forceinline__ unsigned short f2bf(float f) {
    union { float f; unsigned u; } v; v.f = f;
    unsigned u = v.u + 0x7fffu + ((v.u >> 16) & 1u);
    return (unsigned short)(u >> 16);
}

__device__ __forceinline__ float gelu_tanh(float x) {
    float x3 = x * x * x;
    float t = tanhf(0.7978845608028654f * (x + 0.044715f * x3));
    return 0.5f * x * (1.0f + t);
}

__device__ __forceinline__ void gload_lds16(const void* g, void* l) {
    __builtin_amdgcn_global_load_lds(
        (__attribute__((address_space(1))) void*)(uintptr_t)g,
        (__attribute__((address_space(3))) void*)(unsigned)(uintptr_t)l,
        16, 0, 0);
}

// ---------------- fused bias-add + residual + LayerNorm ----------------
__global__ __launch_bounds__(256)
void fused_add_ln(const float* __restrict__ in, const float* __restrict__ res,
                  const float* __restrict__ bias, const float* __restrict__ nw,
                  const float* __restrict__ nb, float* __restrict__ resadd,
                  unsigned short* __restrict__ lnout, int H) {
    const int row = blockIdx.x;
    const int tid = threadIdx.x;
    const size_t base = (size_t)row * H;
    float v[16];
    float s = 0.f, ss = 0.f;
#pragma unroll
    for (int i = 0; i < 4; ++i) {
        int idx = (i * 256 + tid) * 4;
        float4 a = *(const float4*)(in + base + idx);
        float4 b = *(const float4*)(res + base + idx);
        float4 c = *(const float4*)(bias + idx);
        float x0 = a.x + b.x + c.x, x1 = a.y + b.y + c.y;
        float x2 = a.z + b.z + c.z, x3 = a.w + b.w + c.w;
        v[i * 4 + 0] = x0; v[i * 4 + 1] = x1; v[i * 4 + 2] = x2; v[i * 4 + 3] = x3;
        s += x0 + x1 + x2 + x3;
        ss += x0 * x0 + x1 * x1 + x2 * x2 + x3 * x3;
    }
#pragma unroll
    for (int off = 32; off > 0; off >>= 1) {
        s += __shfl_down(s, off);
        ss += __shfl_down(ss, off);
    }
    __shared__ float red[8];
    const int w = tid >> 6;
    if ((tid & 63) == 0) { red[w] = s; red[4 + w] = ss; }
    __syncthreads();
    s = red[0] + red[1] + red[2] + red[3];
    ss = red[4] + red[5] + red[6] + red[7];
    const float mean = s / H;
    const float var = ss / H - mean * mean;
    const float rstd = rsqrtf(var + 1e-12f);
#pragma unroll
    for (int i = 0; i < 4; ++i) {
        int idx = (i * 256 + tid) * 4;
        float4 wv = *(const float4*)(nw + idx);
        float4 bv = *(const float4*)(nb + idx);
        float4 r;
        r.x = v[i * 4 + 0]; r.y = v[i * 4 + 1]; r.z = v[i * 4 + 2]; r.w = v[i * 4 + 3];
        *(float4*)(resadd + base + idx) = r;
        ushort4 o;
        o.x = f2bf((r.x - mean) * rstd * wv.x + bv.x);
        o.y = f2bf((r.y - mean) * rstd * wv.y + bv.y);
        o.z = f2bf((r.z - mean) * rstd * wv.z + bv.z);
        o.w = f2bf((r.w - mean) * rstd * wv.w + bv.w);
        *(ushort4*)(lnout + base + idx) = o;
    }
}

// ---------------- fp32 -> bf16 weight cast ----------------
__global__ __launch_bounds__(256)
void cast_w(const float* __restrict__ w, unsigned short* __restrict__ o, long long n4) {
    long long i = (long long)blockIdx.x * 256 + threadIdx.x;
    if (i >= n4) return;
    float4 f = *(const float4*)(w + i * 4);
    ushort4 u;
    u.x = f2bf(f.x); u.y = f2bf(f.y); u.z = f2bf(f.z); u.w = f2bf(f.w);
    *(ushort4*)(o + i * 4) = u;
}

// ---- 256x256 bf16 GEMM, C = A*B^T: 32x32x16 MFMA, k-slice phases, ------
// ---- read-ahead banks, 2 barriers per 8 phases, 2-bit XOR swizzle ------
// 512 thr = 8 waves (2M x 4N), per-wave 128x64 = 4Mx2N tiles of 32x32.
// R9 finding: swizzle col16 ^= (row&7) alone leaves lanes {l, l+16} (rows
// r, r+16 — same col) conflicting in the b128 mod-16 lane grouping ->
// 5.03e7 bank conflicts. Fix: fold row bit4 into col16 bit1:
//   physical col16 = logical ^ (row&7) ^ (((row>>4)&1) << 1)
// Now {l, l+16, l+32, l+48} hit 4 distinct 16B columns ({hi,bit4} ->
// {0,2,1,3} XOR pattern). Write side stays a linear DMA (only the
// pre-swizzled SOURCE column changes); read applies the same XOR.
// Phase t (8 per iter = 2 K-tiles; ks = K=16 slice):
//   WAIT lgkm(0); 8 MFMA (bank (t-1)&1); [t4,t8: vmcnt(0); BAR];
//   RD 4A+2B (bank t&1); [t1: STG slot1; t5: STG slot0]
// Hazards: stage@t1 after t8's BAR, stage@t5 after t4's BAR; fresh-slot
// reads (t4/t8) follow {gate; BAR} (m104 rule). Waves free-run otherwise.
#define GBM 256
#define GBN 256

#define STAGE(s, mat, h, T) do {                                              \
    const unsigned short* _src = ((mat) ? pB : pA)                            \
        + (size_t)((h) * 128) * K + (size_t)(T) * 64;                         \
    char* _dst = ldsc + (s) * 65536 + (mat) * 32768 + (h) * 16384 + dOff;     \
    gload_lds16(_src, _dst);                                                  \
    gload_lds16(_src + (size_t)64 * K, _dst + 8192);                          \
} while (0)

#define STG(s, T) do { STAGE(s, 0, 0, T); STAGE(s, 0, 1, T);                  \
                       STAGE(s, 1, 0, T); STAGE(s, 1, 1, T); } while (0)

// ds_reads for k-slice ks of slot s into bank b (4 A + 2 B)
#define RD32(b, ks, s) do {                                                   \
    _Pragma("unroll")                                                         \
    for (int m = 0; m < 4; ++m)                                               \
        aq[b][m] = *(const bf16x8*)(ldsc + (s) * 65536                        \
            + ((wr * 128 + m * 32 + l31) << 7) + ck[ks]);                     \
    _Pragma("unroll")                                                         \
    for (int n = 0; n < 2; ++n)                                               \
        bq[b][n] = *(const bf16x8*)(ldsc + (s) * 65536 + 32768                \
            + ((wc * 64 + n * 32 + l31) << 7) + ck[ks]);                      \
} while (0)

#define MF32(b) do {                                                          \
    __builtin_amdgcn_s_setprio(1);                                            \
    _Pragma("unroll")                                                         \
    for (int m = 0; m < 4; ++m)                                               \
        _Pragma("unroll")                                                     \
        for (int n = 0; n < 2; ++n)                                           \
            acc[m][n] = __builtin_amdgcn_mfma_f32_32x32x16_bf16(              \
                aq[b][m], bq[b][n], acc[m][n], 0, 0, 0);                      \
    __builtin_amdgcn_s_setprio(0);                                            \
} while (0)

#define WAITP do { asm volatile("s_waitcnt lgkmcnt(0)" ::: "memory");         \
                   __builtin_amdgcn_sched_barrier(0); } while (0)
#define BAR   asm volatile("s_barrier" ::: "memory")
#define GATE0 asm volatile("s_waitcnt vmcnt(0)" ::: "memory")

template <int EPI>
__global__ __launch_bounds__(512, 2)
void gemm256(const unsigned short* __restrict__ A,
             const unsigned short* __restrict__ B,
             const float* __restrict__ bias_n,
             const float* __restrict__ resadd,
             void* __restrict__ Cout,
             int M, int N, int K) {
    __shared__ unsigned short lds[2][2][256 * 64];  // [slot][A/B][256r x 64k]
    char* ldsc = (char*)&lds[0][0][0];
    const int tid = threadIdx.x;
    const int lane = tid & 63;
    const int w = tid >> 6;
    const int wr = w >> 2;   // 0..1  (M half)
    const int wc = w & 3;    // 0..3  (N quarter)

    const int nwg = gridDim.x;
    const int lg = (blockIdx.x & 7) * (nwg >> 3) + (blockIdx.x >> 3);
    const int nbx = N / GBN;
    const int brow = lg / nbx;
    const int bcol = lg % nbx;

    // staging source (pre-swizzled; 2-bit XOR: (row&7) -> col bit0..2 of
    // col16, row bit4 -> col16 bit1). LDS write stays linear (tid*16).
    const int srow = tid >> 3;                                   // 0..63
    const int scol = ((((tid & 7) << 4) ^ ((srow & 7) << 4)
                      ^ (((srow >> 4) & 1) << 5)) >> 1);         // elements
    const unsigned short* pA = A + (size_t)(brow * GBM + srow) * K + scol;
    const unsigned short* pB = B + (size_t)(bcol * GBN + srow) * K + scol;
    const int dOff = tid * 16;

    // ds_read column bytes per k-slice: logical (ks*32 | hi*16) XOR
    // ((row&7)<<4) XOR ((row bit4)<<5); row bits come from l31.
    const int l31 = lane & 31;
    int ck[4];
#pragma unroll
    for (int ks = 0; ks < 4; ++ks)
        ck[ks] = (((ks << 5) | (((lane >> 5) & 1) << 4))
                  ^ ((lane & 7) << 4) ^ (((lane >> 4) & 1) << 5));

    f32x16 acc[4][2] = {};
    bf16x8 aq[2][4];   // [bank][m-tile]
    bf16x8 bq[2][2];   // [bank][n-tile]

    const int NT = K / 64;
    const int niter = NT / 2;

    // prologue: stage tile0 -> slot0; gate+bar; read ks0 into bank0
    STG(0, 0);
    GATE0; BAR;
    RD32(0, 0, 0);

    for (int i = 0; i < niter - 1; ++i) {
        const int Tn1 = 2 * i + 1, Tn2 = 2 * i + 2;
        WAITP; MF32(0); RD32(1, 1, 0); STG(1, Tn1);     // t1
        WAITP; MF32(1); RD32(0, 2, 0);                  // t2
        WAITP; MF32(0); RD32(1, 3, 0);                  // t3
        WAITP; MF32(1); GATE0; BAR; RD32(0, 0, 1);      // t4 (slot1 ready)
        WAITP; MF32(0); RD32(1, 1, 1); STG(0, Tn2);     // t5
        WAITP; MF32(1); RD32(0, 2, 1);                  // t6
        WAITP; MF32(0); RD32(1, 3, 1);                  // t7
        WAITP; MF32(1); GATE0; BAR; RD32(0, 0, 0);      // t8 (slot0' ready)
    }
    {   // last iteration (tiles NT-2 in slot0, NT-1 in slot1)
        WAITP; MF32(0); RD32(1, 1, 0); STG(1, NT - 1);
        WAITP; MF32(1); RD32(0, 2, 0);
        WAITP; MF32(0); RD32(1, 3, 0);
        WAITP; MF32(1); GATE0; BAR; RD32(0, 0, 1);
        WAITP; MF32(0); RD32(1, 1, 1);
        WAITP; MF32(1); RD32(0, 2, 1);
        WAITP; MF32(0); RD32(1, 3, 1);
        WAITP; MF32(1);
    }

    // epilogue: 32x32 C/D layout col = lane&31,
    // row = (reg&3) + 8*(reg>>2) + 4*(lane>>5)   [m74/m101 verified]
    const int c0 = bcol * GBN + wc * 64 + l31;
    const int r0 = brow * GBM + wr * 128 + ((lane >> 5) & 1) * 4;
#pragma unroll
    for (int m = 0; m < 4; ++m) {
#pragma unroll
        for (int reg = 0; reg < 16; ++reg) {
            const int row = r0 + m * 32 + (reg & 3) + 8 * (reg >> 2);
#pragma unroll
            for (int n = 0; n < 2; ++n) {
                const int col = c0 + n * 32;
                float x = acc[m][n][reg] + bias_n[col];
                if (EPI == 0) {
                    ((unsigned short*)Cout)[(size_t)row * N + col] = f2bf(gelu_tanh(x));
                } else {
                    const size_t off = (size_t)row * N + col;
                    ((float*)Cout)[off] = x + resadd[off];
                }
            }
        }
    }
}

extern "C" void kernel_launch(void* const* d_in, const int* in_sizes, int n_in,
                              void* d_out, int out_size, void* d_ws, size_t ws_size,
                              hipStream_t stream) {
    const float* input    = (const float*)d_in[0];
    const float* residual = (const float*)d_in[1];
    const float* bias     = (const float*)d_in[2];
    const float* attn_nw  = (const float*)d_in[3];
    const float* attn_nb  = (const float*)d_in[4];
    const float* inter_w  = (const float*)d_in[5];
    const float* inter_b  = (const float*)d_in[6];
    const float* output_w = (const float*)d_in[7];
    const float* output_b = (const float*)d_in[8];

    const int H = in_sizes[3];            // 4096
    const int I = in_sizes[6];            // 16384
    const int T = in_sizes[0] / H;        // B*S = 4096

    char* ws = (char*)d_ws;
    float* resadd      = (float*)ws;
    unsigned short* ln = (unsigned short*)(ws + (size_t)T * H * 4);
    unsigned short* w1 = (unsigned short*)((char*)ln + (size_t)T * H * 2);
    unsigned short* w2 = w1 + (size_t)I * H;
    unsigned short* act = w2 + (size_t)H * I;

    fused_add_ln<<<T, 256, 0, stream>>>(input, residual, bias, attn_nw, attn_nb,
                                        resadd, ln, H);

    {
        long long n4 = (long long)I * H / 4;
        int blocks = (int)((n4 + 255) / 256);
        cast_w<<<blocks, 256, 0, stream>>>(inter_w, w1, n4);
        cast_w<<<blocks, 256, 0, stream>>>(output_w, w2, n4);
    }

    // GEMM1: act = gelu(ln @ inter_w^T + inter_b)   [T,I]
    {
        dim3 grid((T / GBM) * (I / GBN));
        gemm256<0><<<grid, 512, 0, stream>>>(ln, w1, inter_b, nullptr, act, T, I, H);
    }

    // GEMM2: out = act @ output_w^T + output_b + resadd   [T,H]
    {
        dim3 grid((T / GBM) * (H / GBN));
        gemm256<1><<<grid, 512, 0, stream>>>(act, w2, output_b, resadd, d_out, T, H, I);
    }
}

// Round 11
// 1199.360 us; speedup vs baseline: 1.1341x; 1.0660x over previous
//
#include <hip/hip_runtime.h>
#include <hip/hip_bf16.h>
#include <cstdint>
#include <math.h>

typedef __attribute__((ext_vector_type(4))) float f32x4;
typedef __attribute__((ext_vector_type(8))) __bf16 bf16x8;

__device__ __forceinline__ unsigned short f2bf(float f) {
    union { float f; unsigned u; } v; v.f = f;
    unsigned u = v.u + 0x7fffu + ((v.u >> 16) & 1u);
    return (unsigned short)(u >> 16);
}

__device__ __forceinline__ float gelu_tanh(float x) {
    float x3 = x * x * x;
    float t = tanhf(0.7978845608028654f * (x + 0.044715f * x3));
    return 0.5f * x * (1.0f + t);
}

__device__ __forceinline__ void gload_lds16(const void* g, void* l) {
    __builtin_amdgcn_global_load_lds(
        (__attribute__((address_space(1))) void*)(uintptr_t)g,
        (__attribute__((address_space(3))) void*)(unsigned)(uintptr_t)l,
        16, 0, 0);
}

// ---------------- fused bias-add + residual + LayerNorm ----------------
__global__ __launch_bounds__(256)
void fused_add_ln(const float* __restrict__ in, const float* __restrict__ res,
                  const float* __restrict__ bias, const float* __restrict__ nw,
                  const float* __restrict__ nb, float* __restrict__ resadd,
                  unsigned short* __restrict__ lnout, int H) {
    const int row = blockIdx.x;
    const int tid = threadIdx.x;
    const size_t base = (size_t)row * H;
    float v[16];
    float s = 0.f, ss = 0.f;
#pragma unroll
    for (int i = 0; i < 4; ++i) {
        int idx = (i * 256 + tid) * 4;
        float4 a = *(const float4*)(in + base + idx);
        float4 b = *(const float4*)(res + base + idx);
        float4 c = *(const float4*)(bias + idx);
        float x0 = a.x + b.x + c.x, x1 = a.y + b.y + c.y;
        float x2 = a.z + b.z + c.z, x3 = a.w + b.w + c.w;
        v[i * 4 + 0] = x0; v[i * 4 + 1] = x1; v[i * 4 + 2] = x2; v[i * 4 + 3] = x3;
        s += x0 + x1 + x2 + x3;
        ss += x0 * x0 + x1 * x1 + x2 * x2 + x3 * x3;
    }
#pragma unroll
    for (int off = 32; off > 0; off >>= 1) {
        s += __shfl_down(s, off);
        ss += __shfl_down(ss, off);
    }
    __shared__ float red[8];
    const int w = tid >> 6;
    if ((tid & 63) == 0) { red[w] = s; red[4 + w] = ss; }
    __syncthreads();
    s = red[0] + red[1] + red[2] + red[3];
    ss = red[4] + red[5] + red[6] + red[7];
    const float mean = s / H;
    const float var = ss / H - mean * mean;
    const float rstd = rsqrtf(var + 1e-12f);
#pragma unroll
    for (int i = 0; i < 4; ++i) {
        int idx = (i * 256 + tid) * 4;
        float4 wv = *(const float4*)(nw + idx);
        float4 bv = *(const float4*)(nb + idx);
        float4 r;
        r.x = v[i * 4 + 0]; r.y = v[i * 4 + 1]; r.z = v[i * 4 + 2]; r.w = v[i * 4 + 3];
        *(float4*)(resadd + base + idx) = r;
        ushort4 o;
        o.x = f2bf((r.x - mean) * rstd * wv.x + bv.x);
        o.y = f2bf((r.y - mean) * rstd * wv.y + bv.y);
        o.z = f2bf((r.z - mean) * rstd * wv.z + bv.z);
        o.w = f2bf((r.w - mean) * rstd * wv.w + bv.w);
        *(ushort4*)(lnout + base + idx) = o;
    }
}

// ---------------- fp32 -> bf16 weight cast ----------------
__global__ __launch_bounds__(256)
void cast_w(const float* __restrict__ w, unsigned short* __restrict__ o, long long n4) {
    long long i = (long long)blockIdx.x * 256 + threadIdx.x;
    if (i >= n4) return;
    float4 f = *(const float4*)(w + i * 4);
    ushort4 u;
    u.x = f2bf(f.x); u.y = f2bf(f.y); u.z = f2bf(f.z); u.w = f2bf(f.w);
    *(ushort4*)(o + i * 4) = u;
}

// ---- 256x256 bf16 GEMM, C = A*B^T: R7's zero-conflict 16x16 reads ------
// ---- + R9's barrier-lite skeleton (2 BARs / 8 phases) + aq read-ahead --
// 512 thr = 8 waves (2M x 4N), per-wave 128x64. LDS 128 KiB, slot = tile&1.
// R10 lesson: the 32x32 read pattern conflicts (5e7, cause unmodellable
// from source); R7's 16x16 pattern measured ZERO. Keep R7 reads verbatim.
// R9 lesson: free-running phases (lgkm-only sync, BAR only at slot
// boundaries) overlap LDS drain with MFMA across waves.
// Phase tN: WAITP(lgkm0+schedbar); MF(q, bank (N-1)&1);
//   [t4,t8: GATE0; BAR; RD_B(fresh slot)]; RD_A(bank N&1, next (q,s));
//   [t1: STG(slot1, T1); t5: STG(slot0, T0+2)]
// Hazards: STG@t1 after t8's {lgkm0 (drained t7 slot1-reads); BAR};
// STG@t5 after t4's {lgkm0; BAR}; fresh-slot reads (t4/t8) after own
// GATE0+BAR (m104: all waves' DMA landed). aq banks alternate; bq single
// bank reloaded at t4/t8 AFTER the MF that consumes the old tile's bq.
// Registers: acc 128 AGPR + aq[2][2][2] 32 + bq[4][2] 32 + addr ~30 -> fits
// the 128 arch budget (512-thr block => 256 unified cap). No spill.
#define GBM 256
#define GBN 256

#define STAGE(s, mat, h, T) do {                                              \
    const unsigned short* _src = ((mat) ? pB : pA)                            \
        + (size_t)((h) * 128) * K + (size_t)(T) * 64;                         \
    char* _dst = ldsc + (s) * 65536 + (mat) * 32768 + (h) * 16384 + dOff;     \
    gload_lds16(_src, _dst);                                                  \
    gload_lds16(_src + (size_t)64 * K, _dst + 8192);                          \
} while (0)

#define STG(s, T) do { STAGE(s, 0, 0, T); STAGE(s, 0, 1, T);                  \
                       STAGE(s, 1, 0, T); STAGE(s, 1, 1, T); } while (0)

#define RD_B(s) do {                                                          \
    _Pragma("unroll")                                                         \
    for (int ni = 0; ni < 4; ++ni)                                            \
        _Pragma("unroll")                                                     \
        for (int kk = 0; kk < 2; ++kk)                                        \
            bq[ni][kk] = *(const bf16x8*)(ldsc + (s) * 65536 + 32768          \
                + ((wc * 64 + ni * 16 + lrow) << 7) + ckk[kk]);               \
} while (0)

#define RD_A(bk, q, s) do {                                                   \
    _Pragma("unroll")                                                         \
    for (int m2 = 0; m2 < 2; ++m2)                                            \
        _Pragma("unroll")                                                     \
        for (int kk = 0; kk < 2; ++kk)                                        \
            aq[bk][m2][kk] = *(const bf16x8*)(ldsc + (s) * 65536              \
                + ((wr * 128 + ((q) * 2 + m2) * 16 + lrow) << 7) + ckk[kk]);  \
} while (0)

#define MF(q, bk) do {                                                        \
    __builtin_amdgcn_s_setprio(1);                                            \
    _Pragma("unroll")                                                         \
    for (int m2 = 0; m2 < 2; ++m2)                                            \
        _Pragma("unroll")                                                     \
        for (int ni = 0; ni < 4; ++ni)                                        \
            _Pragma("unroll")                                                 \
            for (int kk = 0; kk < 2; ++kk)                                    \
                acc[(q) * 2 + m2][ni] = __builtin_amdgcn_mfma_f32_16x16x32_bf16( \
                    aq[bk][m2][kk], bq[ni][kk], acc[(q) * 2 + m2][ni], 0, 0, 0); \
    __builtin_amdgcn_s_setprio(0);                                            \
} while (0)

#define WAITP do { asm volatile("s_waitcnt lgkmcnt(0)" ::: "memory");         \
                   __builtin_amdgcn_sched_barrier(0); } while (0)
#define BAR   asm volatile("s_barrier" ::: "memory")
#define GATE0 asm volatile("s_waitcnt vmcnt(0)" ::: "memory")

template <int EPI>
__global__ __launch_bounds__(512, 2)
void gemm256(const unsigned short* __restrict__ A,
             const unsigned short* __restrict__ B,
             const float* __restrict__ bias_n,
             const float* __restrict__ resadd,
             void* __restrict__ Cout,
             int M, int N, int K) {
    __shared__ unsigned short lds[2][2][2][128 * 64];  // [slot][A/B][half][.]
    char* ldsc = (char*)&lds[0][0][0][0];
    const int tid = threadIdx.x;
    const int lane = tid & 63;
    const int w = tid >> 6;
    const int wr = w >> 2;   // 0..1
    const int wc = w & 3;    // 0..3

    const int nwg = gridDim.x;
    const int lg = (blockIdx.x & 7) * (nwg >> 3) + (blockIdx.x >> 3);
    const int nbx = N / GBN;
    const int brow = lg / nbx;
    const int bcol = lg % nbx;

    // staging source (pre-swizzled; R7 formulas verbatim)
    const int srow = tid >> 3;                                   // 0..63
    const int scol = ((((tid & 7) << 4) ^ ((srow & 7) << 4)) >> 1);
    const unsigned short* pA = A + (size_t)(brow * GBM + srow) * K + scol;
    const unsigned short* pB = B + (size_t)(bcol * GBN + srow) * K + scol;
    const int dOff = tid * 16;

    // ds_read column bytes (R7 verbatim: zero measured conflicts)
    const int lrow = lane & 15;
    int ckk[2];
    ckk[0] = (((lane >> 4) << 4)) ^ ((lrow & 7) << 4);
    ckk[1] = ckk[0] ^ 64;

    f32x4 acc[8][4] = {};
    bf16x8 aq[2][2][2];  // [bank][m2][kk] — bank alternates per phase
    bf16x8 bq[4][2];     // single bank, reloaded at fresh-slot phases

    const int NT = K / 64;
    const int niter = NT / 2;

    // prologue: stage tile0 -> slot0; gate+bar; read B and A(q0) bank0
    STG(0, 0);
    GATE0; BAR;
    RD_B(0); RD_A(0, 0, 0);

    for (int i = 0; i < niter - 1; ++i) {
        const int T1 = 2 * i + 1, T2 = 2 * i + 2;
        WAITP; MF(0, 0); RD_A(1, 1, 0); STG(1, T1);          // t1
        WAITP; MF(1, 1); RD_A(0, 2, 0);                      // t2
        WAITP; MF(2, 0); RD_A(1, 3, 0);                      // t3
        WAITP; MF(3, 1); GATE0; BAR; RD_B(1); RD_A(0, 0, 1); // t4 (slot1 ok)
        WAITP; MF(0, 0); RD_A(1, 1, 1); STG(0, T2);          // t5
        WAITP; MF(1, 1); RD_A(0, 2, 1);                      // t6
        WAITP; MF(2, 0); RD_A(1, 3, 1);                      // t7
        WAITP; MF(3, 1); GATE0; BAR; RD_B(0); RD_A(0, 0, 0); // t8 (slot0' ok)
    }
    {   // peeled last iteration (tiles NT-2 slot0, NT-1 slot1)
        WAITP; MF(0, 0); RD_A(1, 1, 0); STG(1, NT - 1);
        WAITP; MF(1, 1); RD_A(0, 2, 0);
        WAITP; MF(2, 0); RD_A(1, 3, 0);
        WAITP; MF(3, 1); GATE0; BAR; RD_B(1); RD_A(0, 0, 1);
        WAITP; MF(0, 0); RD_A(1, 1, 1);
        WAITP; MF(1, 1); RD_A(0, 2, 1);
        WAITP; MF(2, 0); RD_A(1, 3, 1);
        WAITP; MF(3, 1);
    }

    // epilogue: C/D layout col = lane&15, row = (lane>>4)*4 + j
    const int c0 = bcol * GBN + wc * 64 + lrow;
    const int r0 = brow * GBM + wr * 128 + (lane >> 4) * 4;
#pragma unroll
    for (int mi = 0; mi < 8; ++mi) {
#pragma unroll
        for (int j = 0; j < 4; ++j) {
            const int row = r0 + mi * 16 + j;
#pragma unroll
            for (int ni = 0; ni < 4; ++ni) {
                const int col = c0 + ni * 16;
                float x = acc[mi][ni][j] + bias_n[col];
                if (EPI == 0) {
                    ((unsigned short*)Cout)[(size_t)row * N + col] = f2bf(gelu_tanh(x));
                } else {
                    const size_t off = (size_t)row * N + col;
                    ((float*)Cout)[off] = x + resadd[off];
                }
            }
        }
    }
}

extern "C" void kernel_launch(void* const* d_in, const int* in_sizes, int n_in,
                              void* d_out, int out_size, void* d_ws, size_t ws_size,
                              hipStream_t stream) {
    const float* input    = (const float*)d_in[0];
    const float* residual = (const float*)d_in[1];
    const float* bias     = (const float*)d_in[2];
    const float* attn_nw  = (const float*)d_in[3];
    const float* attn_nb  = (const float*)d_in[4];
    const float* inter_w  = (const float*)d_in[5];
    const float* inter_b  = (const float*)d_in[6];
    const float* output_w = (const float*)d_in[7];
    const float* output_b = (const float*)d_in[8];

    const int H = in_sizes[3];            // 4096
    const int I = in_sizes[6];            // 16384
    const int T = in_sizes[0] / H;        // B*S = 4096

    char* ws = (char*)d_ws;
    float* resadd      = (float*)ws;
    unsigned short* ln = (unsigned short*)(ws + (size_t)T * H * 4);
    unsigned short* w1 = (unsigned short*)((char*)ln + (size_t)T * H * 2);
    unsigned short* w2 = w1 + (size_t)I * H;
    unsigned short* act = w2 + (size_t)H * I;

    fused_add_ln<<<T, 256, 0, stream>>>(input, residual, bias, attn_nw, attn_nb,
                                        resadd, ln, H);

    {
        long long n4 = (long long)I * H / 4;
        int blocks = (int)((n4 + 255) / 256);
        cast_w<<<blocks, 256, 0, stream>>>(inter_w, w1, n4);
        cast_w<<<blocks, 256, 0, stream>>>(output_w, w2, n4);
    }

    // GEMM1: act = gelu(ln @ inter_w^T + inter_b)   [T,I]
    {
        dim3 grid((T / GBM) * (I / GBN));
        gemm256<0><<<grid, 512, 0, stream>>>(ln, w1, inter_b, nullptr, act, T, I, H);
    }

    // GEMM2: out = act @ output_w^T + output_b + resadd   [T,H]
    {
        dim3 grid((T / GBM) * (H / GBN));
        gemm256<1><<<grid, 512, 0, stream>>>(act, w2, output_b, resadd, d_out, T, H, I);
    }
}